// Round 1
// baseline (1340.266 us; speedup 1.0000x reference)
//
#include <hip/hip_runtime.h>

#define NN   100000
#define EE   3200000
#define KDIM 1433
#define HID  16
#define OUTD 7

// ---- gemm1 tiling ----
#define KC    128
#define RB    64
#define XSTR  133            // 133 % 32 = 5 (odd, coprime) -> 2-way LDS aliasing = free
#define NCHUNK ((KDIM + KC - 1) / KC)   // 12

__global__ void k_init_deg(float* __restrict__ deg) {
    int i = blockIdx.x * blockDim.x + threadIdx.x;
    if (i < NN) deg[i] = 1.0f;           // self-loop contributes 1
}

__global__ void k_deg(const int* __restrict__ ei, float* __restrict__ deg) {
    int e = blockIdx.x * blockDim.x + threadIdx.x;
    if (e < EE) atomicAdd(&deg[ei[e]], 1.0f);   // row = ei[0][e]
}

__global__ void k_dinv(float* __restrict__ deg) {
    int i = blockIdx.x * blockDim.x + threadIdx.x;
    if (i < NN) deg[i] = rsqrtf(deg[i]);        // deg >= 1 always
}

// h1[N][16] = x[N][1433] @ W1[1433][16]
__global__ __launch_bounds__(256) void k_gemm1(const float* __restrict__ x,
                                               const float* __restrict__ W1,
                                               float* __restrict__ h1) {
    __shared__ __align__(16) float xs[RB * XSTR];   // 34 KB -> 4 blocks/CU
    const int tid = threadIdx.x;
    const int w   = tid >> 6;     // wave 0..3 (k-split)
    const int L   = tid & 63;     // lane = local row
    const int r0  = blockIdx.x * RB;

    float acc[HID];
#pragma unroll
    for (int j = 0; j < HID; ++j) acc[j] = 0.f;

    for (int c = 0; c < NCHUNK; ++c) {
        const int c0 = c * KC;
        const int kvalid = (KDIM - c0 < KC) ? (KDIM - c0) : KC;
        __syncthreads();
        // stage 64 rows x 128 k, coalesced dword loads
#pragma unroll
        for (int m = 0; m < (RB * KC) / 256; ++m) {   // 32
            int idx = m * 256 + tid;
            int rr  = idx >> 7;          // / KC
            int kk  = idx & (KC - 1);
            int gr  = r0 + rr;
            float v = 0.f;
            if (gr < NN && kk < kvalid) v = x[(size_t)gr * KDIM + c0 + kk];
            xs[rr * XSTR + kk] = v;
        }
        __syncthreads();
        // wave w covers kk in [w*32, w*32+32); W1 row address is wave-uniform -> scalar loads
        int kend = kvalid - w * 32;
        if (kend > 32) kend = 32;
        for (int i = 0; i < kend; ++i) {
            int kk = w * 32 + i;
            float xv = xs[L * XSTR + kk];
            const float4* wrow = reinterpret_cast<const float4*>(W1 + (size_t)(c0 + kk) * HID);
            float4 w0 = wrow[0], w1 = wrow[1], w2 = wrow[2], w3 = wrow[3];
            acc[0]  = fmaf(xv, w0.x, acc[0]);
            acc[1]  = fmaf(xv, w0.y, acc[1]);
            acc[2]  = fmaf(xv, w0.z, acc[2]);
            acc[3]  = fmaf(xv, w0.w, acc[3]);
            acc[4]  = fmaf(xv, w1.x, acc[4]);
            acc[5]  = fmaf(xv, w1.y, acc[5]);
            acc[6]  = fmaf(xv, w1.z, acc[6]);
            acc[7]  = fmaf(xv, w1.w, acc[7]);
            acc[8]  = fmaf(xv, w2.x, acc[8]);
            acc[9]  = fmaf(xv, w2.y, acc[9]);
            acc[10] = fmaf(xv, w2.z, acc[10]);
            acc[11] = fmaf(xv, w2.w, acc[11]);
            acc[12] = fmaf(xv, w3.x, acc[12]);
            acc[13] = fmaf(xv, w3.y, acc[13]);
            acc[14] = fmaf(xv, w3.z, acc[14]);
            acc[15] = fmaf(xv, w3.w, acc[15]);
        }
    }
    __syncthreads();
    // cross-wave k-reduction via LDS (alias xs; 16 KB needed <= 34 KB)
    float4* red4 = reinterpret_cast<float4*>(xs);
    red4[(w * 64 + L) * 4 + 0] = make_float4(acc[0], acc[1], acc[2], acc[3]);
    red4[(w * 64 + L) * 4 + 1] = make_float4(acc[4], acc[5], acc[6], acc[7]);
    red4[(w * 64 + L) * 4 + 2] = make_float4(acc[8], acc[9], acc[10], acc[11]);
    red4[(w * 64 + L) * 4 + 3] = make_float4(acc[12], acc[13], acc[14], acc[15]);
    __syncthreads();
    int rr = tid >> 2, jj = tid & 3;
    float4 a = red4[(0 * 64 + rr) * 4 + jj];
    float4 b = red4[(1 * 64 + rr) * 4 + jj];
    float4 cfr = red4[(2 * 64 + rr) * 4 + jj];
    float4 d = red4[(3 * 64 + rr) * 4 + jj];
    float4 s = make_float4(a.x + b.x + cfr.x + d.x, a.y + b.y + cfr.y + d.y,
                           a.z + b.z + cfr.z + d.z, a.w + b.w + cfr.w + d.w);
    int gr = r0 + rr;
    if (gr < NN) reinterpret_cast<float4*>(h1)[(size_t)gr * 4 + jj] = s;
}

// agg1[i][j] = h1[i][j] * dinv[i]^2   (self-loop term initializes the accumulator)
__global__ void k_selfloop1(const float* __restrict__ h1, const float* __restrict__ dinv,
                            float* __restrict__ agg1) {
    int t = blockIdx.x * blockDim.x + threadIdx.x;
    if (t >= NN * HID) return;
    int i = t >> 4;
    float di = dinv[i];
    agg1[t] = h1[t] * di * di;
}

// thread per (edge, feature): agg1[row][j] += h1[col][j] * dinv[row]*dinv[col]
__global__ void k_scatter1(const int* __restrict__ ei, const float* __restrict__ dinv,
                           const float* __restrict__ h1, float* __restrict__ agg1) {
    int t = blockIdx.x * blockDim.x + threadIdx.x;
    int e = t >> 4, j = t & 15;
    if (e >= EE) return;
    int r = ei[e], c = ei[EE + e];
    float nrm = dinv[r] * dinv[c];
    atomicAdd(&agg1[(size_t)r * HID + j], h1[(size_t)c * HID + j] * nrm);
}

// h2[i][0..7) = relu(agg1[i] + b1) @ W2
__global__ void k_mlp2(const float* __restrict__ agg1, const float* __restrict__ b1,
                       const float* __restrict__ W2, float* __restrict__ h2) {
    int i = blockIdx.x * blockDim.x + threadIdx.x;
    if (i >= NN) return;
    const float4* a4 = reinterpret_cast<const float4*>(agg1 + (size_t)i * HID);
    float4 t0 = a4[0], t1 = a4[1], t2 = a4[2], t3 = a4[3];
    float v[16] = {t0.x, t0.y, t0.z, t0.w, t1.x, t1.y, t1.z, t1.w,
                   t2.x, t2.y, t2.z, t2.w, t3.x, t3.y, t3.z, t3.w};
#pragma unroll
    for (int k = 0; k < 16; ++k) v[k] = fmaxf(v[k] + b1[k], 0.f);
    float o[7] = {0.f, 0.f, 0.f, 0.f, 0.f, 0.f, 0.f};
#pragma unroll
    for (int k = 0; k < 16; ++k)
#pragma unroll
        for (int j = 0; j < 7; ++j) o[j] = fmaf(v[k], W2[k * 7 + j], o[j]);
#pragma unroll
    for (int j = 0; j < 7; ++j) h2[(size_t)i * OUTD + j] = o[j];
}

__global__ void k_selfloop2(const float* __restrict__ h2, const float* __restrict__ dinv,
                            float* __restrict__ agg2) {
    int t = blockIdx.x * blockDim.x + threadIdx.x;
    int i = t >> 3, j = t & 7;
    if (i >= NN || j >= OUTD) return;
    float di = dinv[i];
    agg2[(size_t)i * OUTD + j] = h2[(size_t)i * OUTD + j] * di * di;
}

__global__ void k_scatter2(const int* __restrict__ ei, const float* __restrict__ dinv,
                           const float* __restrict__ h2, float* __restrict__ agg2) {
    int t = blockIdx.x * blockDim.x + threadIdx.x;
    int e = t >> 3, j = t & 7;
    if (e >= EE || j >= OUTD) return;
    int r = ei[e], c = ei[EE + e];
    float nrm = dinv[r] * dinv[c];
    atomicAdd(&agg2[(size_t)r * OUTD + j], h2[(size_t)c * OUTD + j] * nrm);
}

__global__ void k_logsoftmax(const float* __restrict__ agg2, const float* __restrict__ b2,
                             float* __restrict__ out) {
    int i = blockIdx.x * blockDim.x + threadIdx.x;
    if (i >= NN) return;
    float v[7];
#pragma unroll
    for (int j = 0; j < 7; ++j) v[j] = agg2[(size_t)i * OUTD + j] + b2[j];
    float m = v[0];
#pragma unroll
    for (int j = 1; j < 7; ++j) m = fmaxf(m, v[j]);
    float ssum = 0.f;
#pragma unroll
    for (int j = 0; j < 7; ++j) ssum += expf(v[j] - m);
    float ls = logf(ssum);
#pragma unroll
    for (int j = 0; j < 7; ++j) out[(size_t)i * OUTD + j] = v[j] - m - ls;
}

extern "C" void kernel_launch(void* const* d_in, const int* in_sizes, int n_in,
                              void* d_out, int out_size, void* d_ws, size_t ws_size,
                              hipStream_t stream) {
    const float* x  = (const float*)d_in[0];
    const int*   ei = (const int*)d_in[1];     // [2, E] flattened, int32
    const float* W1 = (const float*)d_in[2];
    const float* b1 = (const float*)d_in[3];
    const float* W2 = (const float*)d_in[4];
    const float* b2 = (const float*)d_in[5];
    float* out = (float*)d_out;
    float* ws  = (float*)d_ws;

    float* dinv = ws;                       // N
    float* h1   = ws + NN;                  // 16N
    float* agg1 = ws + NN + 16 * NN;        // 16N   (peak ws: 33N floats = 13.2 MB)
    float* h2   = h1;                       // 7N, reuses dead h1
    float* agg2 = agg1;                     // 7N, reuses dead agg1

    hipLaunchKernelGGL(k_init_deg, dim3((NN + 255) / 256), dim3(256), 0, stream, dinv);
    hipLaunchKernelGGL(k_deg, dim3((EE + 255) / 256), dim3(256), 0, stream, ei, dinv);
    hipLaunchKernelGGL(k_dinv, dim3((NN + 255) / 256), dim3(256), 0, stream, dinv);
    hipLaunchKernelGGL(k_gemm1, dim3((NN + RB - 1) / RB), dim3(256), 0, stream, x, W1, h1);
    hipLaunchKernelGGL(k_selfloop1, dim3((NN * HID + 255) / 256), dim3(256), 0, stream,
                       h1, dinv, agg1);
    hipLaunchKernelGGL(k_scatter1, dim3((EE * HID) / 256), dim3(256), 0, stream,
                       ei, dinv, h1, agg1);
    hipLaunchKernelGGL(k_mlp2, dim3((NN + 255) / 256), dim3(256), 0, stream,
                       agg1, b1, W2, h2);
    hipLaunchKernelGGL(k_selfloop2, dim3((NN * 8 + 255) / 256), dim3(256), 0, stream,
                       h2, dinv, agg2);
    hipLaunchKernelGGL(k_scatter2, dim3((EE * 8) / 256), dim3(256), 0, stream,
                       ei, dinv, h2, agg2);
    hipLaunchKernelGGL(k_logsoftmax, dim3((NN + 255) / 256), dim3(256), 0, stream,
                       agg2, b2, out);
}